// Round 1
// baseline (961.228 us; speedup 1.0000x reference)
//
#include <hip/hip_runtime.h>
#include <cstdint>
#include <cstddef>

typedef __bf16 bf16_t;
typedef __attribute__((ext_vector_type(8))) __bf16 bf16x8;
typedef __attribute__((ext_vector_type(4))) __bf16 bf16x4;
typedef __attribute__((ext_vector_type(4))) float floatx4;

#define NB 32
#define NW 168
#define NM 2048
#define NHID 128
#define NBW (NB * NW)  // 5376

__device__ inline bf16x8 zero_bf16x8() {
  bf16x8 z;
#pragma unroll
  for (int i = 0; i < 8; ++i) z[i] = (bf16_t)0.0f;
  return z;
}

// elementwise fp32 -> bf16 cast, n4 = n/4
__global__ void cast_bf16_kernel(const float* __restrict__ in, bf16_t* __restrict__ out, int n4) {
  int stride = gridDim.x * blockDim.x;
  for (int i = blockIdx.x * blockDim.x + threadIdx.x; i < n4; i += stride) {
    float4 v = ((const float4*)in)[i];
    bf16x4 o = {(bf16_t)v.x, (bf16_t)v.y, (bf16_t)v.z, (bf16_t)v.w};
    ((bf16x4*)out)[i] = o;
  }
}

// out[c][r] = (bf16) in[r][c]; R, C multiples of 64. 64x64 tile via LDS.
__global__ void transpose_cast_kernel(const float* __restrict__ in, bf16_t* __restrict__ out,
                                      int R, int C) {
  __shared__ float tile[64][65];
  int r0 = blockIdx.y * 64, c0 = blockIdx.x * 64;
  int t = threadIdx.x;
  int tr = t >> 4, tc4 = (t & 15) * 4;
#pragma unroll
  for (int p = 0; p < 4; ++p) {
    int row = p * 16 + tr;
    float4 v = *(const float4*)(in + (size_t)(r0 + row) * C + c0 + tc4);
    tile[row][tc4 + 0] = v.x;
    tile[row][tc4 + 1] = v.y;
    tile[row][tc4 + 2] = v.z;
    tile[row][tc4 + 3] = v.w;
  }
  __syncthreads();
#pragma unroll
  for (int p = 0; p < 4; ++p) {
    int c = p * 16 + tr;
    bf16x4 o = {(bf16_t)tile[tc4 + 0][c], (bf16_t)tile[tc4 + 1][c],
                (bf16_t)tile[tc4 + 2][c], (bf16_t)tile[tc4 + 3][c]};
    *(bf16x4*)(out + (size_t)(c0 + c) * R + r0 + tc4) = o;
  }
}

// NT GEMM: C[m,n] = sum_k A[m,k]*Bt[n,k].  M,N multiples of 128, K multiple of 32.
// 128x128 tile, 4 waves, each wave 64x64 (4x4 MFMA 16x16x32 subtiles). C written bf16.
__global__ void gemm_nt_kernel(const bf16_t* __restrict__ A, const bf16_t* __restrict__ Bt,
                               bf16_t* __restrict__ C, int K, int lda, int ldb, int ldc) {
  __shared__ bf16_t As[128 * 40];
  __shared__ bf16_t Bs[128 * 40];
  int tid = threadIdx.x;
  int m0 = blockIdx.y * 128, n0 = blockIdx.x * 128;
  int lane = tid & 63, wv = tid >> 6;
  int wm = wv >> 1, wn = wv & 1;
  int quad = lane >> 4, l15 = lane & 15;
  // staging mapping: 512 chunks of 8 bf16; chunk -> (row, koff)
  int ch0 = tid * 2;
  int row0 = ch0 >> 2, k0 = (ch0 & 3) * 8;
  int row1 = (ch0 + 1) >> 2, k1 = ((ch0 + 1) & 3) * 8;
  const bf16_t* a0p = A + (size_t)(m0 + row0) * lda + k0;
  const bf16_t* a1p = A + (size_t)(m0 + row1) * lda + k1;
  const bf16_t* b0p = Bt + (size_t)(n0 + row0) * ldb + k0;
  const bf16_t* b1p = Bt + (size_t)(n0 + row1) * ldb + k1;

  floatx4 zero4 = {0.f, 0.f, 0.f, 0.f};
  floatx4 acc[4][4];
#pragma unroll
  for (int mi = 0; mi < 4; ++mi)
#pragma unroll
    for (int ni = 0; ni < 4; ++ni) acc[mi][ni] = zero4;

  for (int kb = 0; kb < K; kb += 32) {
    bf16x8 a0 = *(const bf16x8*)(a0p + kb);
    bf16x8 a1 = *(const bf16x8*)(a1p + kb);
    bf16x8 b0 = *(const bf16x8*)(b0p + kb);
    bf16x8 b1 = *(const bf16x8*)(b1p + kb);
    *(bf16x8*)(As + row0 * 40 + k0) = a0;
    *(bf16x8*)(As + row1 * 40 + k1) = a1;
    *(bf16x8*)(Bs + row0 * 40 + k0) = b0;
    *(bf16x8*)(Bs + row1 * 40 + k1) = b1;
    __syncthreads();
    bf16x8 af[4], bf[4];
#pragma unroll
    for (int mi = 0; mi < 4; ++mi)
      af[mi] = *(const bf16x8*)(As + (wm * 64 + mi * 16 + l15) * 40 + quad * 8);
#pragma unroll
    for (int ni = 0; ni < 4; ++ni)
      bf[ni] = *(const bf16x8*)(Bs + (wn * 64 + ni * 16 + l15) * 40 + quad * 8);
#pragma unroll
    for (int mi = 0; mi < 4; ++mi)
#pragma unroll
      for (int ni = 0; ni < 4; ++ni)
        acc[mi][ni] = __builtin_amdgcn_mfma_f32_16x16x32_bf16(af[mi], bf[ni], acc[mi][ni], 0, 0, 0);
    __syncthreads();
  }
#pragma unroll
  for (int mi = 0; mi < 4; ++mi) {
#pragma unroll
    for (int ni = 0; ni < 4; ++ni) {
      int col = n0 + wn * 64 + ni * 16 + l15;
#pragma unroll
      for (int r = 0; r < 4; ++r) {
        int row = m0 + wm * 64 + mi * 16 + quad * 4 + r;
        C[(size_t)row * ldc + col] = (bf16_t)acc[mi][ni][r];
      }
    }
  }
}

// Fused per-hop MLP + score: rows r = m*32+b (128 per block), T row at
// (r>>5)*NBW + (r&31)*NW, K=168 (padded to 192 with zeros), N=HID=128.
// score = sum_h relu(H+b1)*W2 + b2 -> out[b*NM+m]  (store if accumulate==0 else +=)
__global__ void mlp_score_kernel(const bf16_t* __restrict__ T, const bf16_t* __restrict__ W1b,
                                 const float* __restrict__ b1, const float* __restrict__ W2,
                                 const float* __restrict__ b2, float* __restrict__ out,
                                 int hop, int accumulate) {
  __shared__ bf16_t As[128 * 40];
  __shared__ bf16_t Bs[128 * 40];
  __shared__ float sred[4][64];
  const bf16_t* Wh = W1b + (size_t)hop * NHID * NW;
  const float* b1h = b1 + hop * NHID;
  const float* w2h = W2 + hop * NHID;
  int tid = threadIdx.x;
  int r0 = blockIdx.x * 128;
  int lane = tid & 63, wv = tid >> 6;
  int wm = wv >> 1, wn = wv & 1;
  int quad = lane >> 4, l15 = lane & 15;
  int ch0 = tid * 2;
  int row0 = ch0 >> 2, k0 = (ch0 & 3) * 8;
  int row1 = (ch0 + 1) >> 2, k1 = ((ch0 + 1) & 3) * 8;
  int R0 = r0 + row0, R1 = r0 + row1;
  const bf16_t* arow0 = T + (size_t)(R0 >> 5) * NBW + (size_t)(R0 & 31) * NW;
  const bf16_t* arow1 = T + (size_t)(R1 >> 5) * NBW + (size_t)(R1 & 31) * NW;

  floatx4 zero4 = {0.f, 0.f, 0.f, 0.f};
  floatx4 acc[4][4];
#pragma unroll
  for (int mi = 0; mi < 4; ++mi)
#pragma unroll
    for (int ni = 0; ni < 4; ++ni) acc[mi][ni] = zero4;

  for (int kb = 0; kb < 192; kb += 32) {
    bf16x8 a0 = zero_bf16x8();
    bf16x8 a1 = a0, bb0 = a0, bb1 = a0;
    if (kb + k0 < NW) {  // chunks are 8-aligned; 168%8==0 so chunks are all-in or all-out
      a0 = *(const bf16x8*)(arow0 + kb + k0);
      bb0 = *(const bf16x8*)(Wh + (size_t)row0 * NW + kb + k0);
    }
    if (kb + k1 < NW) {
      a1 = *(const bf16x8*)(arow1 + kb + k1);
      bb1 = *(const bf16x8*)(Wh + (size_t)row1 * NW + kb + k1);
    }
    *(bf16x8*)(As + row0 * 40 + k0) = a0;
    *(bf16x8*)(As + row1 * 40 + k1) = a1;
    *(bf16x8*)(Bs + row0 * 40 + k0) = bb0;
    *(bf16x8*)(Bs + row1 * 40 + k1) = bb1;
    __syncthreads();
    bf16x8 af[4], bf[4];
#pragma unroll
    for (int mi = 0; mi < 4; ++mi)
      af[mi] = *(const bf16x8*)(As + (wm * 64 + mi * 16 + l15) * 40 + quad * 8);
#pragma unroll
    for (int ni = 0; ni < 4; ++ni)
      bf[ni] = *(const bf16x8*)(Bs + (wn * 64 + ni * 16 + l15) * 40 + quad * 8);
#pragma unroll
    for (int mi = 0; mi < 4; ++mi)
#pragma unroll
      for (int ni = 0; ni < 4; ++ni)
        acc[mi][ni] = __builtin_amdgcn_mfma_f32_16x16x32_bf16(af[mi], bf[ni], acc[mi][ni], 0, 0, 0);
    __syncthreads();
  }

  // epilogue: relu(H + b1) dot W2 per row
  float part[4][4];
#pragma unroll
  for (int mi = 0; mi < 4; ++mi)
#pragma unroll
    for (int r = 0; r < 4; ++r) part[mi][r] = 0.f;
#pragma unroll
  for (int ni = 0; ni < 4; ++ni) {
    int col = wn * 64 + ni * 16 + l15;
    float b1v = b1h[col];
    float w2v = w2h[col];
#pragma unroll
    for (int mi = 0; mi < 4; ++mi)
#pragma unroll
      for (int r = 0; r < 4; ++r) {
        float h = acc[mi][ni][r] + b1v;
        h = h > 0.f ? h : 0.f;
        part[mi][r] += h * w2v;
      }
  }
#pragma unroll
  for (int off = 1; off < 16; off <<= 1)
#pragma unroll
    for (int mi = 0; mi < 4; ++mi)
#pragma unroll
      for (int r = 0; r < 4; ++r) part[mi][r] += __shfl_xor(part[mi][r], off);
  if (l15 == 0) {
#pragma unroll
    for (int mi = 0; mi < 4; ++mi)
#pragma unroll
      for (int r = 0; r < 4; ++r) sred[wv][mi * 16 + quad * 4 + r] = part[mi][r];
  }
  __syncthreads();
  if (tid < 128) {
    int half = tid >> 6;  // 0: rows 0-63 (waves 0,1); 1: rows 64-127 (waves 2,3)
    int lr = tid & 63;
    float v = sred[half * 2][lr] + sred[half * 2 + 1][lr] + b2[hop];
    int R = r0 + half * 64 + lr;
    int idx = (R & 31) * NM + (R >> 5);  // out[b*M + m]
    if (accumulate)
      out[idx] += v;
    else
      out[idx] = v;
  }
}

extern "C" void kernel_launch(void* const* d_in, const int* in_sizes, int n_in,
                              void* d_out, int out_size, void* d_ws, size_t ws_size,
                              hipStream_t stream) {
  const float* x = (const float*)d_in[0];
  const float* L = (const float*)d_in[1];
  const float* W1 = (const float*)d_in[2];
  const float* b1 = (const float*)d_in[3];
  const float* W2 = (const float*)d_in[4];
  const float* b2 = (const float*)d_in[5];
  float* out = (float*)d_out;

  char* ws = (char*)d_ws;
  size_t off = 0;
  auto walloc = [&](size_t bytes) -> void* {
    off = (off + 255) & ~(size_t)255;
    void* p = ws + off;
    off += bytes;
    return p;
  };
  bf16_t* Xb = (bf16_t*)walloc((size_t)NBW * NM * 2);   // x cast: [(b,w)][m] = X^T for NT
  bf16_t* XT = (bf16_t*)walloc((size_t)NM * NBW * 2);   // x transposed [(m)][(b,w)]; reused as T
  bf16_t* Lb = (bf16_t*)walloc((size_t)NM * NM * 2);    // L bf16 (= P_1)
  bf16_t* Ltb = (bf16_t*)walloc((size_t)NM * NM * 2);   // L^T bf16
  bf16_t* W1b = (bf16_t*)walloc((size_t)7 * NHID * NW * 2);
  bf16_t* Pa = (bf16_t*)walloc((size_t)NM * NM * 2);
  bf16_t* Pb = (bf16_t*)walloc((size_t)NM * NM * 2);
  (void)ws_size; (void)in_sizes; (void)n_in; (void)out_size;

  cast_bf16_kernel<<<dim3(1024), dim3(256), 0, stream>>>(x, Xb, NB * NW * NM / 4);
  cast_bf16_kernel<<<dim3(1024), dim3(256), 0, stream>>>(L, Lb, NM * NM / 4);
  cast_bf16_kernel<<<dim3(64), dim3(256), 0, stream>>>(W1, W1b, 7 * NHID * NW / 4);
  transpose_cast_kernel<<<dim3(NM / 64, NBW / 64), dim3(256), 0, stream>>>(x, XT, NBW, NM);
  transpose_cast_kernel<<<dim3(NM / 64, NM / 64), dim3(256), 0, stream>>>(L, Ltb, NM, NM);

  // hop 0: identity propagation, input is XT
  mlp_score_kernel<<<dim3(NM * NB / 128), dim3(256), 0, stream>>>(XT, W1b, b1, W2, b2, out, 0, 0);

  const bf16_t* P = Lb;
  bf16_t* Pbufs[2] = {Pa, Pb};
  int pi = 0;
  bf16_t* Tb = XT;  // hop0 consumed XT already; safe to reuse (stream-serialized)
  for (int i = 1; i <= 6; ++i) {
    // T = P @ X  (NT: A=P row-major, B^T = Xb)
    gemm_nt_kernel<<<dim3(NBW / 128, NM / 128), dim3(256), 0, stream>>>(P, Xb, Tb, NM, NM, NM, NBW);
    mlp_score_kernel<<<dim3(NM * NB / 128), dim3(256), 0, stream>>>(Tb, W1b, b1, W2, b2, out, i, 1);
    if (i < 6) {
      // P_{i+1} = P_i @ L  (powers commute; NT: B^T = (L^T)^T handled via Ltb)
      bf16_t* Pn = Pbufs[pi];
      pi ^= 1;
      gemm_nt_kernel<<<dim3(NM / 128, NM / 128), dim3(256), 0, stream>>>(P, Ltb, Pn, NM, NM, NM, NM);
      P = Pn;
    }
  }
}

// Round 2
// 578.593 us; speedup vs baseline: 1.6613x; 1.6613x over previous
//
#include <hip/hip_runtime.h>
#include <cstdint>
#include <cstddef>

typedef __bf16 bf16_t;
typedef __attribute__((ext_vector_type(8))) __bf16 bf16x8;
typedef __attribute__((ext_vector_type(4))) __bf16 bf16x4;
typedef __attribute__((ext_vector_type(4))) float floatx4;

#define NB 32
#define NW 168
#define NM 2048
#define NHID 128
#define NBW (NB * NW)  // 5376

#define GLOAD_LDS16(g, l)                                          \
  __builtin_amdgcn_global_load_lds(                                \
      (const __attribute__((address_space(1))) void*)(g),          \
      (__attribute__((address_space(3))) void*)(l), 16, 0, 0)

__device__ inline bf16x8 zero_bf16x8() {
  bf16x8 z;
#pragma unroll
  for (int i = 0; i < 8; ++i) z[i] = (bf16_t)0.0f;
  return z;
}

// elementwise fp32 -> bf16 cast, n4 = n/4
__global__ void cast_bf16_kernel(const float* __restrict__ in, bf16_t* __restrict__ out, int n4) {
  int stride = gridDim.x * blockDim.x;
  for (int i = blockIdx.x * blockDim.x + threadIdx.x; i < n4; i += stride) {
    float4 v = ((const float4*)in)[i];
    bf16x4 o = {(bf16_t)v.x, (bf16_t)v.y, (bf16_t)v.z, (bf16_t)v.w};
    ((bf16x4*)out)[i] = o;
  }
}

// out[c][r] = (bf16) in[r][c]; R, C multiples of 64. fp32 in.
__global__ void transpose_cast_kernel(const float* __restrict__ in, bf16_t* __restrict__ out,
                                      int R, int C) {
  __shared__ float tile[64][65];
  int r0 = blockIdx.y * 64, c0 = blockIdx.x * 64;
  int t = threadIdx.x;
  int tr = t >> 4, tc4 = (t & 15) * 4;
#pragma unroll
  for (int p = 0; p < 4; ++p) {
    int row = p * 16 + tr;
    float4 v = *(const float4*)(in + (size_t)(r0 + row) * C + c0 + tc4);
    tile[row][tc4 + 0] = v.x;
    tile[row][tc4 + 1] = v.y;
    tile[row][tc4 + 2] = v.z;
    tile[row][tc4 + 3] = v.w;
  }
  __syncthreads();
#pragma unroll
  for (int p = 0; p < 4; ++p) {
    int c = p * 16 + tr;
    bf16x4 o = {(bf16_t)tile[tc4 + 0][c], (bf16_t)tile[tc4 + 1][c],
                (bf16_t)tile[tc4 + 2][c], (bf16_t)tile[tc4 + 3][c]};
    *(bf16x4*)(out + (size_t)(c0 + c) * R + r0 + tc4) = o;
  }
}

// bf16 transpose: out[c][r] = in[r][c]; R, C multiples of 64.
__global__ void transpose_bf16_kernel(const bf16_t* __restrict__ in, bf16_t* __restrict__ out,
                                      int R, int C) {
  __shared__ bf16_t tile[64][80];  // 80: keeps b128 writes 16B-aligned
  int r0 = blockIdx.y * 64, c0 = blockIdx.x * 64;
  int t = threadIdx.x;
  int lr = t >> 3;         // 0..31
  int lc = (t & 7) * 8;    // 0..56
#pragma unroll
  for (int p = 0; p < 2; ++p) {
    int row = p * 32 + lr;
    bf16x8 v = *(const bf16x8*)(in + (size_t)(r0 + row) * C + c0 + lc);
    *(bf16x8*)(&tile[row][lc]) = v;
  }
  __syncthreads();
#pragma unroll
  for (int p = 0; p < 2; ++p) {
    int oc = p * 32 + lr;
    bf16x8 v;
#pragma unroll
    for (int j = 0; j < 8; ++j) v[j] = tile[lc + j][oc];
    *(bf16x8*)(out + (size_t)(c0 + oc) * R + r0 + lc) = v;
  }
}

// NT GEMM with async global->LDS staging (m97 structure):
// C[m,n] = sum_k A[m,k]*Bt[n,k].  M,N multiples of 128, K multiple of 32.
// 128x128 tile, 4 waves, each 64x64 (4x4 MFMA 16x16x32). Unpadded LDS 128x32,
// XOR-swizzled on the global-source side: chunk p holds (row=p>>2, kc=(p&3)^((p>>3)&3)).
__global__ void gemm_nt_kernel(const bf16_t* __restrict__ A, const bf16_t* __restrict__ Bt,
                               bf16_t* __restrict__ C, int K, int lda, int ldb, int ldc) {
  __shared__ bf16_t As[128 * 32];
  __shared__ bf16_t Bs[128 * 32];
  int tid = threadIdx.x;
  int m0 = blockIdx.y * 128, n0 = blockIdx.x * 128;
  int lane = tid & 63, wv = tid >> 6;
  int wm = wv >> 1, wn = wv & 1;
  int quad = lane >> 4, l15 = lane & 15;

  // staging: wave wv handles chunks [wv*128, wv*128+128) per buffer; 2 calls of 64
  int p0 = wv * 128 + lane;
  int p1 = p0 + 64;
  int row0 = p0 >> 2, kc0 = (p0 & 3) ^ ((p0 >> 3) & 3);
  int row1 = p1 >> 2, kc1 = (p1 & 3) ^ ((p1 >> 3) & 3);
  const bf16_t* a0p = A + (size_t)(m0 + row0) * lda + kc0 * 8;
  const bf16_t* a1p = A + (size_t)(m0 + row1) * lda + kc1 * 8;
  const bf16_t* b0p = Bt + (size_t)(n0 + row0) * ldb + kc0 * 8;
  const bf16_t* b1p = Bt + (size_t)(n0 + row1) * ldb + kc1 * 8;
  bf16_t* As_d0 = As + (size_t)(wv * 128) * 8;
  bf16_t* As_d1 = As + (size_t)(wv * 128 + 64) * 8;
  bf16_t* Bs_d0 = Bs + (size_t)(wv * 128) * 8;
  bf16_t* Bs_d1 = Bs + (size_t)(wv * 128 + 64) * 8;

  // fragment-read swizzle: kc position = quad ^ ((l15>>1)&3)  (row-dependent part
  // reduces to l15 since mi*16 and wm*64 are 0 mod 8 after >>1 &3)
  int swz = (l15 >> 1) & 3;
  int kpos = (quad ^ swz) * 8;

  floatx4 zero4 = {0.f, 0.f, 0.f, 0.f};
  floatx4 acc[4][4];
#pragma unroll
  for (int mi = 0; mi < 4; ++mi)
#pragma unroll
    for (int ni = 0; ni < 4; ++ni) acc[mi][ni] = zero4;

  for (int kb = 0; kb < K; kb += 32) {
    GLOAD_LDS16(a0p + kb, As_d0);
    GLOAD_LDS16(a1p + kb, As_d1);
    GLOAD_LDS16(b0p + kb, Bs_d0);
    GLOAD_LDS16(b1p + kb, Bs_d1);
    __syncthreads();
    bf16x8 af[4], bf[4];
#pragma unroll
    for (int mi = 0; mi < 4; ++mi)
      af[mi] = *(const bf16x8*)(As + (wm * 64 + mi * 16 + l15) * 32 + kpos);
#pragma unroll
    for (int ni = 0; ni < 4; ++ni)
      bf[ni] = *(const bf16x8*)(Bs + (wn * 64 + ni * 16 + l15) * 32 + kpos);
#pragma unroll
    for (int mi = 0; mi < 4; ++mi)
#pragma unroll
      for (int ni = 0; ni < 4; ++ni)
        acc[mi][ni] = __builtin_amdgcn_mfma_f32_16x16x32_bf16(af[mi], bf[ni], acc[mi][ni], 0, 0, 0);
    __syncthreads();
  }
#pragma unroll
  for (int mi = 0; mi < 4; ++mi) {
#pragma unroll
    for (int ni = 0; ni < 4; ++ni) {
      int col = n0 + wn * 64 + ni * 16 + l15;
#pragma unroll
      for (int r = 0; r < 4; ++r) {
        int row = m0 + wm * 64 + mi * 16 + quad * 4 + r;
        C[(size_t)row * ldc + col] = (bf16_t)acc[mi][ni][r];
      }
    }
  }
}

// Fused per-hop MLP + score: rows r = m*32+b (128 per block), T row at
// (r>>5)*NBW + (r&31)*NW, K=168 (padded to 192 with zeros), N=HID=128.
// score = sum_h relu(H+b1)*W2 + b2 -> out[b*NM+m]  (store if accumulate==0 else +=)
__global__ void mlp_score_kernel(const bf16_t* __restrict__ T, const bf16_t* __restrict__ W1b,
                                 const float* __restrict__ b1, const float* __restrict__ W2,
                                 const float* __restrict__ b2, float* __restrict__ out,
                                 int hop, int accumulate) {
  __shared__ bf16_t As[128 * 40];
  __shared__ bf16_t Bs[128 * 40];
  __shared__ float sred[4][64];
  const bf16_t* Wh = W1b + (size_t)hop * NHID * NW;
  const float* b1h = b1 + hop * NHID;
  const float* w2h = W2 + hop * NHID;
  int tid = threadIdx.x;
  int r0 = blockIdx.x * 128;
  int lane = tid & 63, wv = tid >> 6;
  int wm = wv >> 1, wn = wv & 1;
  int quad = lane >> 4, l15 = lane & 15;
  int ch0 = tid * 2;
  int row0 = ch0 >> 2, k0 = (ch0 & 3) * 8;
  int row1 = (ch0 + 1) >> 2, k1 = ((ch0 + 1) & 3) * 8;
  int R0 = r0 + row0, R1 = r0 + row1;
  const bf16_t* arow0 = T + (size_t)(R0 >> 5) * NBW + (size_t)(R0 & 31) * NW;
  const bf16_t* arow1 = T + (size_t)(R1 >> 5) * NBW + (size_t)(R1 & 31) * NW;

  floatx4 zero4 = {0.f, 0.f, 0.f, 0.f};
  floatx4 acc[4][4];
#pragma unroll
  for (int mi = 0; mi < 4; ++mi)
#pragma unroll
    for (int ni = 0; ni < 4; ++ni) acc[mi][ni] = zero4;

  for (int kb = 0; kb < 192; kb += 32) {
    bf16x8 a0 = zero_bf16x8();
    bf16x8 a1 = a0, bb0 = a0, bb1 = a0;
    if (kb + k0 < NW) {  // chunks 8-aligned; 168%8==0 so all-in or all-out
      a0 = *(const bf16x8*)(arow0 + kb + k0);
      bb0 = *(const bf16x8*)(Wh + (size_t)row0 * NW + kb + k0);
    }
    if (kb + k1 < NW) {
      a1 = *(const bf16x8*)(arow1 + kb + k1);
      bb1 = *(const bf16x8*)(Wh + (size_t)row1 * NW + kb + k1);
    }
    *(bf16x8*)(As + row0 * 40 + k0) = a0;
    *(bf16x8*)(As + row1 * 40 + k1) = a1;
    *(bf16x8*)(Bs + row0 * 40 + k0) = bb0;
    *(bf16x8*)(Bs + row1 * 40 + k1) = bb1;
    __syncthreads();
    bf16x8 af[4], bf[4];
#pragma unroll
    for (int mi = 0; mi < 4; ++mi)
      af[mi] = *(const bf16x8*)(As + (wm * 64 + mi * 16 + l15) * 40 + quad * 8);
#pragma unroll
    for (int ni = 0; ni < 4; ++ni)
      bf[ni] = *(const bf16x8*)(Bs + (wn * 64 + ni * 16 + l15) * 40 + quad * 8);
#pragma unroll
    for (int mi = 0; mi < 4; ++mi)
#pragma unroll
      for (int ni = 0; ni < 4; ++ni)
        acc[mi][ni] = __builtin_amdgcn_mfma_f32_16x16x32_bf16(af[mi], bf[ni], acc[mi][ni], 0, 0, 0);
    __syncthreads();
  }

  // epilogue: relu(H + b1) dot W2 per row
  float part[4][4];
#pragma unroll
  for (int mi = 0; mi < 4; ++mi)
#pragma unroll
    for (int r = 0; r < 4; ++r) part[mi][r] = 0.f;
#pragma unroll
  for (int ni = 0; ni < 4; ++ni) {
    int col = wn * 64 + ni * 16 + l15;
    float b1v = b1h[col];
    float w2v = w2h[col];
#pragma unroll
    for (int mi = 0; mi < 4; ++mi)
#pragma unroll
      for (int r = 0; r < 4; ++r) {
        float h = acc[mi][ni][r] + b1v;
        h = h > 0.f ? h : 0.f;
        part[mi][r] += h * w2v;
      }
  }
#pragma unroll
  for (int off = 1; off < 16; off <<= 1)
#pragma unroll
    for (int mi = 0; mi < 4; ++mi)
#pragma unroll
      for (int r = 0; r < 4; ++r) part[mi][r] += __shfl_xor(part[mi][r], off);
  if (l15 == 0) {
#pragma unroll
    for (int mi = 0; mi < 4; ++mi)
#pragma unroll
      for (int r = 0; r < 4; ++r) sred[wv][mi * 16 + quad * 4 + r] = part[mi][r];
  }
  __syncthreads();
  if (tid < 128) {
    int half = tid >> 6;
    int lr = tid & 63;
    float v = sred[half * 2][lr] + sred[half * 2 + 1][lr] + b2[hop];
    int R = r0 + half * 64 + lr;
    int idx = (R & 31) * NM + (R >> 5);  // out[b*M + m]
    if (accumulate)
      out[idx] += v;
    else
      out[idx] = v;
  }
}

extern "C" void kernel_launch(void* const* d_in, const int* in_sizes, int n_in,
                              void* d_out, int out_size, void* d_ws, size_t ws_size,
                              hipStream_t stream) {
  const float* x = (const float*)d_in[0];
  const float* L = (const float*)d_in[1];
  const float* W1 = (const float*)d_in[2];
  const float* b1 = (const float*)d_in[3];
  const float* W2 = (const float*)d_in[4];
  const float* b2 = (const float*)d_in[5];
  float* out = (float*)d_out;

  char* ws = (char*)d_ws;
  size_t off = 0;
  auto walloc = [&](size_t bytes) -> void* {
    off = (off + 255) & ~(size_t)255;
    void* p = ws + off;
    off += bytes;
    return p;
  };
  bf16_t* Xb = (bf16_t*)walloc((size_t)NBW * NM * 2);   // Tt_0 = x cast: [(b,w)][m]
  bf16_t* XT = (bf16_t*)walloc((size_t)NM * NBW * 2);   // [m][(b,w)] MLP input (reused per hop)
  bf16_t* Lb = (bf16_t*)walloc((size_t)NM * NM * 2);    // L bf16 (NT B-operand: Bt[m][k]=L[m][k])
  bf16_t* W1b = (bf16_t*)walloc((size_t)7 * NHID * NW * 2);
  bf16_t* Ta = (bf16_t*)walloc((size_t)NBW * NM * 2);   // ping-pong partner of Xb
  (void)ws_size; (void)in_sizes; (void)n_in; (void)out_size;

  cast_bf16_kernel<<<dim3(1024), dim3(256), 0, stream>>>(x, Xb, NB * NW * NM / 4);
  cast_bf16_kernel<<<dim3(1024), dim3(256), 0, stream>>>(L, Lb, NM * NM / 4);
  cast_bf16_kernel<<<dim3(64), dim3(256), 0, stream>>>(W1, W1b, 7 * NHID * NW / 4);
  transpose_cast_kernel<<<dim3(NM / 64, NBW / 64), dim3(256), 0, stream>>>(x, XT, NBW, NM);

  // hop 0: identity propagation
  mlp_score_kernel<<<dim3(NM * NB / 128), dim3(256), 0, stream>>>(XT, W1b, b1, W2, b2, out, 0, 0);

  // T-chain: Tt_i[(bw)][m] = sum_k Tt_{i-1}[(bw)][k] * L[m][k]   (NT, Bt = Lb)
  bf16_t* src = Xb;
  bf16_t* dst = Ta;
  for (int i = 1; i <= 6; ++i) {
    gemm_nt_kernel<<<dim3(NM / 128, NBW / 128), dim3(256), 0, stream>>>(
        src, Lb, dst, NM, NM, NM, NM);
    transpose_bf16_kernel<<<dim3(NM / 64, NBW / 64), dim3(256), 0, stream>>>(dst, XT, NBW, NM);
    mlp_score_kernel<<<dim3(NM * NB / 128), dim3(256), 0, stream>>>(XT, W1b, b1, W2, b2, out, i, 1);
    bf16_t* t = src; src = dst; dst = t;
  }
}

// Round 3
// 552.652 us; speedup vs baseline: 1.7393x; 1.0469x over previous
//
#include <hip/hip_runtime.h>
#include <cstdint>
#include <cstddef>

typedef __bf16 bf16_t;
typedef __attribute__((ext_vector_type(8))) __bf16 bf16x8;
typedef __attribute__((ext_vector_type(4))) __bf16 bf16x4;
typedef __attribute__((ext_vector_type(4))) float floatx4;

#define NB 32
#define NW 168
#define NM 2048
#define NHID 128
#define NBW (NB * NW)  // 5376

#define GLOAD_LDS16(g, l)                                          \
  __builtin_amdgcn_global_load_lds(                                \
      (const __attribute__((address_space(1))) void*)(g),          \
      (__attribute__((address_space(3))) void*)(l), 16, 0, 0)

// elementwise fp32 -> bf16 cast, n4 = n/4
__global__ void cast_bf16_kernel(const float* __restrict__ in, bf16_t* __restrict__ out, int n4) {
  int stride = gridDim.x * blockDim.x;
  for (int i = blockIdx.x * blockDim.x + threadIdx.x; i < n4; i += stride) {
    float4 v = ((const float4*)in)[i];
    bf16x4 o = {(bf16_t)v.x, (bf16_t)v.y, (bf16_t)v.z, (bf16_t)v.w};
    ((bf16x4*)out)[i] = o;
  }
}

// Fused x prep: read x [(bw)][m] fp32 once; write Xb [(bw)][m] bf16 (cast) and
// XT [m][(bw)] bf16 (transpose). 64x64 tiles.
__global__ void prep_x_kernel(const float* __restrict__ x, bf16_t* __restrict__ Xb,
                              bf16_t* __restrict__ XT) {
  __shared__ float tile[64][65];
  const int R = NBW, C = NM;
  int r0 = blockIdx.y * 64, c0 = blockIdx.x * 64;
  int t = threadIdx.x;
  int tr = t >> 4, tc4 = (t & 15) * 4;
#pragma unroll
  for (int p = 0; p < 4; ++p) {
    int row = p * 16 + tr;
    float4 v = *(const float4*)(x + (size_t)(r0 + row) * C + c0 + tc4);
    tile[row][tc4 + 0] = v.x;
    tile[row][tc4 + 1] = v.y;
    tile[row][tc4 + 2] = v.z;
    tile[row][tc4 + 3] = v.w;
    bf16x4 o = {(bf16_t)v.x, (bf16_t)v.y, (bf16_t)v.z, (bf16_t)v.w};
    *(bf16x4*)(Xb + (size_t)(r0 + row) * C + c0 + tc4) = o;
  }
  __syncthreads();
#pragma unroll
  for (int p = 0; p < 4; ++p) {
    int c = p * 16 + tr;
    bf16x4 o = {(bf16_t)tile[tc4 + 0][c], (bf16_t)tile[tc4 + 1][c],
                (bf16_t)tile[tc4 + 2][c], (bf16_t)tile[tc4 + 3][c]};
    *(bf16x4*)(XT + (size_t)(c0 + c) * R + r0 + tc4) = o;
  }
}

// NT GEMM with async global->LDS staging + fused transposed output:
// C[m,n] = sum_k A[m,k]*Bt[n,k];  Ct[n][m] written as bf16x4 (4 consecutive
// C-rows per fragment are contiguous in Ct). write_c==0 skips the C store.
__global__ void gemm_nt_kernel(const bf16_t* __restrict__ A, const bf16_t* __restrict__ Bt,
                               bf16_t* __restrict__ C, bf16_t* __restrict__ Ct,
                               int K, int lda, int ldb, int ldc, int ldct, int write_c) {
  __shared__ bf16_t As[128 * 32];
  __shared__ bf16_t Bs[128 * 32];
  int tid = threadIdx.x;
  int m0 = blockIdx.y * 128, n0 = blockIdx.x * 128;
  int lane = tid & 63, wv = tid >> 6;
  int wm = wv >> 1, wn = wv & 1;
  int quad = lane >> 4, l15 = lane & 15;

  // staging: wave wv handles chunks [wv*128, wv*128+128) per buffer; 2 calls of 64
  int p0 = wv * 128 + lane;
  int p1 = p0 + 64;
  int row0 = p0 >> 2, kc0 = (p0 & 3) ^ ((p0 >> 3) & 3);
  int row1 = p1 >> 2, kc1 = (p1 & 3) ^ ((p1 >> 3) & 3);
  const bf16_t* a0p = A + (size_t)(m0 + row0) * lda + kc0 * 8;
  const bf16_t* a1p = A + (size_t)(m0 + row1) * lda + kc1 * 8;
  const bf16_t* b0p = Bt + (size_t)(n0 + row0) * ldb + kc0 * 8;
  const bf16_t* b1p = Bt + (size_t)(n0 + row1) * ldb + kc1 * 8;
  bf16_t* As_d0 = As + (size_t)(wv * 128) * 8;
  bf16_t* As_d1 = As + (size_t)(wv * 128 + 64) * 8;
  bf16_t* Bs_d0 = Bs + (size_t)(wv * 128) * 8;
  bf16_t* Bs_d1 = Bs + (size_t)(wv * 128 + 64) * 8;

  // fragment-read swizzle: kc position = quad ^ ((l15>>1)&3)
  int swz = (l15 >> 1) & 3;
  int kpos = (quad ^ swz) * 8;

  floatx4 zero4 = {0.f, 0.f, 0.f, 0.f};
  floatx4 acc[4][4];
#pragma unroll
  for (int mi = 0; mi < 4; ++mi)
#pragma unroll
    for (int ni = 0; ni < 4; ++ni) acc[mi][ni] = zero4;

  for (int kb = 0; kb < K; kb += 32) {
    GLOAD_LDS16(a0p + kb, As_d0);
    GLOAD_LDS16(a1p + kb, As_d1);
    GLOAD_LDS16(b0p + kb, Bs_d0);
    GLOAD_LDS16(b1p + kb, Bs_d1);
    __syncthreads();
    bf16x8 af[4], bf[4];
#pragma unroll
    for (int mi = 0; mi < 4; ++mi)
      af[mi] = *(const bf16x8*)(As + (wm * 64 + mi * 16 + l15) * 32 + kpos);
#pragma unroll
    for (int ni = 0; ni < 4; ++ni)
      bf[ni] = *(const bf16x8*)(Bs + (wn * 64 + ni * 16 + l15) * 32 + kpos);
#pragma unroll
    for (int mi = 0; mi < 4; ++mi)
#pragma unroll
      for (int ni = 0; ni < 4; ++ni)
        acc[mi][ni] = __builtin_amdgcn_mfma_f32_16x16x32_bf16(af[mi], bf[ni], acc[mi][ni], 0, 0, 0);
    __syncthreads();
  }
#pragma unroll
  for (int mi = 0; mi < 4; ++mi) {
#pragma unroll
    for (int ni = 0; ni < 4; ++ni) {
      int col = n0 + wn * 64 + ni * 16 + l15;
      int rowb = m0 + wm * 64 + mi * 16 + quad * 4;
      bf16x4 tv;
#pragma unroll
      for (int r = 0; r < 4; ++r) tv[r] = (bf16_t)acc[mi][ni][r];
      // transposed store: Ct[col][rowb..rowb+3] contiguous
      *(bf16x4*)(Ct + (size_t)col * ldct + rowb) = tv;
      if (write_c) {
#pragma unroll
        for (int r = 0; r < 4; ++r)
          C[(size_t)(rowb + r) * ldc + col] = tv[r];
      }
    }
  }
}

// Fused per-hop MLP + score. Rows r = m*32+b (128 per block); T row (m,b) at
// m*NBW + b*NW in XT. K=168 padded to 192: W1 staged once into LDS in [kc][h]
// chunk layout (kc 21..23 zeroed, so no A-side predication needed: A garbage
// times B zero contributes 0). A fragments read directly from global.
// score = sum_h relu(H+b1)*W2 + b2 -> out[b*NM+m]
__global__ void mlp_score_kernel(const bf16_t* __restrict__ T, const bf16_t* __restrict__ W1b,
                                 const float* __restrict__ b1, const float* __restrict__ W2,
                                 const float* __restrict__ b2, float* __restrict__ out,
                                 int hop, int accumulate) {
  __shared__ bf16_t Bs[24 * 128 * 8];  // 48 KB: chunk (kc,h_pos) at (kc*128+h_pos)*8
  __shared__ float sred[4][64];
  const bf16_t* Wh = W1b + (size_t)hop * NHID * NW;
  const float* b1h = b1 + hop * NHID;
  const float* w2h = W2 + hop * NHID;
  int tid = threadIdx.x;
  int r0 = blockIdx.x * 128;
  int lane = tid & 63, wv = tid >> 6;
  int wm = wv >> 1, wn = wv & 1;
  int quad = lane >> 4, l15 = lane & 15;

  // zero the pad chunks [2688, 3072) = kc 21..23
  for (int c = 2688 + tid; c < 3072; c += 256) {
    int4 z = {0, 0, 0, 0};
    *(int4*)(Bs + (size_t)c * 8) = z;
  }
  // stage 2688 valid chunks; LDS pos c -> kc=c>>7, h = (c&127) ^ ((kc&3)<<2)
  for (int i = 0; i < 11; ++i) {
    int c = i * 256 + tid;
    if (c < 2688) {  // 2688 = 42 full waves: no partial-wave exec masks
      int kc = c >> 7;
      int h = (c & 127) ^ ((kc & 3) << 2);
      GLOAD_LDS16(Wh + (size_t)h * NW + kc * 8, Bs + (size_t)(i * 256 + wv * 64) * 8);
    }
  }

  // A row pointers (per mi): row index R = r0 + wm*64 + mi*16 + l15
  const bf16_t* arow[4];
#pragma unroll
  for (int mi = 0; mi < 4; ++mi) {
    int R = r0 + wm * 64 + mi * 16 + l15;
    arow[mi] = T + (size_t)(R >> 5) * NBW + (size_t)(R & 31) * NW + quad * 8;
  }

  floatx4 zero4 = {0.f, 0.f, 0.f, 0.f};
  floatx4 acc[4][4];
#pragma unroll
  for (int mi = 0; mi < 4; ++mi)
#pragma unroll
    for (int ni = 0; ni < 4; ++ni) acc[mi][ni] = zero4;

  __syncthreads();  // staging (incl. async loads) complete

#pragma unroll
  for (int kb = 0; kb < 192; kb += 32) {
    int kc = (kb >> 3) + quad;
    bf16x8 af[4], bf[4];
#pragma unroll
    for (int mi = 0; mi < 4; ++mi)
      af[mi] = *(const bf16x8*)(arow[mi] + kb);  // k>=168 reads garbage; B pad=0
#pragma unroll
    for (int ni = 0; ni < 4; ++ni) {
      int hpos = (wn * 64 + ni * 16 + l15) ^ ((kc & 3) << 2);
      bf[ni] = *(const bf16x8*)(Bs + (size_t)(kc * 128 + hpos) * 8);
    }
#pragma unroll
    for (int mi = 0; mi < 4; ++mi)
#pragma unroll
      for (int ni = 0; ni < 4; ++ni)
        acc[mi][ni] = __builtin_amdgcn_mfma_f32_16x16x32_bf16(af[mi], bf[ni], acc[mi][ni], 0, 0, 0);
  }

  // epilogue: relu(H + b1) dot W2 per row
  float part[4][4];
#pragma unroll
  for (int mi = 0; mi < 4; ++mi)
#pragma unroll
    for (int r = 0; r < 4; ++r) part[mi][r] = 0.f;
#pragma unroll
  for (int ni = 0; ni < 4; ++ni) {
    int col = wn * 64 + ni * 16 + l15;
    float b1v = b1h[col];
    float w2v = w2h[col];
#pragma unroll
    for (int mi = 0; mi < 4; ++mi)
#pragma unroll
      for (int r = 0; r < 4; ++r) {
        float h = acc[mi][ni][r] + b1v;
        h = h > 0.f ? h : 0.f;
        part[mi][r] += h * w2v;
      }
  }
#pragma unroll
  for (int off = 1; off < 16; off <<= 1)
#pragma unroll
    for (int mi = 0; mi < 4; ++mi)
#pragma unroll
      for (int r = 0; r < 4; ++r) part[mi][r] += __shfl_xor(part[mi][r], off);
  if (l15 == 0) {
#pragma unroll
    for (int mi = 0; mi < 4; ++mi)
#pragma unroll
      for (int r = 0; r < 4; ++r) sred[wv][mi * 16 + quad * 4 + r] = part[mi][r];
  }
  __syncthreads();
  if (tid < 128) {
    int half = tid >> 6;
    int lr = tid & 63;
    float v = sred[half * 2][lr] + sred[half * 2 + 1][lr] + b2[hop];
    int R = r0 + half * 64 + lr;
    int idx = (R & 31) * NM + (R >> 5);  // out[b*M + m]
    if (accumulate)
      out[idx] += v;
    else
      out[idx] = v;
  }
}

extern "C" void kernel_launch(void* const* d_in, const int* in_sizes, int n_in,
                              void* d_out, int out_size, void* d_ws, size_t ws_size,
                              hipStream_t stream) {
  const float* x = (const float*)d_in[0];
  const float* L = (const float*)d_in[1];
  const float* W1 = (const float*)d_in[2];
  const float* b1 = (const float*)d_in[3];
  const float* W2 = (const float*)d_in[4];
  const float* b2 = (const float*)d_in[5];
  float* out = (float*)d_out;

  char* ws = (char*)d_ws;
  size_t off = 0;
  auto walloc = [&](size_t bytes) -> void* {
    off = (off + 255) & ~(size_t)255;
    void* p = ws + off;
    off += bytes;
    return p;
  };
  bf16_t* Xb = (bf16_t*)walloc((size_t)NBW * NM * 2);   // Tt_0 = x cast: [(b,w)][m]
  bf16_t* XT = (bf16_t*)walloc((size_t)NM * NBW * 2);   // [m][(b,w)] MLP input (per hop)
  bf16_t* Lb = (bf16_t*)walloc((size_t)NM * NM * 2);    // L bf16 (NT B-operand)
  bf16_t* W1b = (bf16_t*)walloc((size_t)7 * NHID * NW * 2);
  bf16_t* Ta = (bf16_t*)walloc((size_t)NBW * NM * 2);   // ping-pong partner of Xb
  (void)ws_size; (void)in_sizes; (void)n_in; (void)out_size;

  prep_x_kernel<<<dim3(NM / 64, NBW / 64), dim3(256), 0, stream>>>(x, Xb, XT);
  cast_bf16_kernel<<<dim3(1024), dim3(256), 0, stream>>>(L, Lb, NM * NM / 4);
  cast_bf16_kernel<<<dim3(64), dim3(256), 0, stream>>>(W1, W1b, 7 * NHID * NW / 4);

  // hop 0: identity propagation
  mlp_score_kernel<<<dim3(NM * NB / 128), dim3(256), 0, stream>>>(XT, W1b, b1, W2, b2, out, 0, 0);

  // T-chain: Tt_i[(bw)][m] = sum_k Tt_{i-1}[(bw)][k] * L[m][k]   (NT, Bt = Lb)
  // Epilogue writes both Tt_i (for next hop) and XT = Tt_i^T (for the MLP).
  bf16_t* src = Xb;
  bf16_t* dst = Ta;
  for (int i = 1; i <= 6; ++i) {
    gemm_nt_kernel<<<dim3(NM / 128, NBW / 128), dim3(256), 0, stream>>>(
        src, Lb, dst, XT, NM, NM, NM, NM, NBW, (i < 6) ? 1 : 0);
    mlp_score_kernel<<<dim3(NM * NB / 128), dim3(256), 0, stream>>>(XT, W1b, b1, W2, b2, out, i, 1);
    bf16_t* t = src; src = dst; dst = t;
  }
}